// Round 14
// baseline (3518.528 us; speedup 1.0000x reference)
//
#include <hip/hip_runtime.h>

// ---------------------------------------------------------------------------
// LSTM  T=2048, B=64, D=256, H=256  (fp32 in/out, bf16 MFMA compute)
//
//   G[t,b,c] = x[t,b,:] @ Wx[:,c] + bias[c]          (parallel GEMM)
//   per step: pre[c] = G[t,b,c] + h[t-1] @ Wh[:,c]   (persistent recurrent krn)
//   gates f,i,g,o -> c = f*c + i*g ; h = o*tanh(c)
//
// Round-14 = round-11 baseline (3212us verified: round-1 structure + Tc=512 +
// packed-bf16 G + launch_bounds(512,1) + bar3) with ONE change:
// SOFTWARE-PIPELINED 2-DEEP POLLING.
//   Old: serial poll, one pair + vmcnt(0) per retry -> sampling period = RTT
//        (~500-700cy); a just-missed publish wastes up to a full RTT/step.
//   New: two pairs (A,B) kept in flight, alternately re-armed; each check
//        waits vmcnt(2) (drains only the OLDER pair; stores/G are older
//        still). Sampling period ~RTT/2, checked data at most one RTT old.
//   FAIL-SAFE BY PROTOCOL: every accepted word is per-u32 tag-checked.
//   Un-landed/garbage register -> wrong tag -> retry. WAW leftover from a
//   previous step's address -> old tag -> retry. Mid-check overwrite can
//   only deposit a same-tag snapshot = bit-identical (producer cannot
//   advance this parity buffer past tag t until we publish t+1).
//   FIFO accounting (verified): at each vmcnt(2) the only ops younger than
//   the checked pair are the other pair's 2 loads. tl==0 prologue: weights/
//   creg/G loads are older -> drained by the first vmcnt(2).
//   Leftover pair at success: drained as "oldest" by next step's vmcnt(2).
// Round-13 lesson (NEUTRAL): Tc 512->256 halved FETCH exactly but per-step
// time identical -> chunk gradient exhausted; revert to Tc=512.
// Round-12 lesson: bar3 is performance-load-bearing (+36% without: wave
// de-phasing multiplies retry quantization). Keep.
// Round-11 lesson: VGPR_Count=40 is fine — loop-invariant MFMA operands live
// in AGPRs (unified file); weights were always resident.
//
// Recurrent kernel: 4 batch-groups (M=16) x 8 column-slice WGs (128 cols each).
// h exchange FENCE-FREE via self-describing u32 words:
//   word = (tag << 16) | bf16(h),  tag = t+1  (tags <= 2048 < 2^16)
// All exchange traffic uses the agent-scope UC path (bypasses per-XCD L2s ->
// correct for ANY workgroup placement; no L2-residency staleness, no fences).
// Termination: a word cannot advance past tag t until this reader's WG
// publishes t+1 (parity double buffer). Overwrite safety: publishing tag t+1
// requires having observed tag t from ALL slices => all finished reading t-1.
// In-loop barriers are s_waitcnt lgkmcnt(0); s_barrier (LDS-only ordering);
// publish/out store-acks drain inside the poll's vmcnt(2) (they are older).
// hbuf MUST be 128 KB (earlier sessions hung: 64 KB aliased cstate over tags).
// Mode-A (same-XCD L2 exchange) abandoned: sc0 polls can cache stale clean
// lines (livelock / silent cross-replay corruption) without L2 inv/wb ops.
// Round-8 lesson: HIP predefines ushort4 -> use ushort4v.
// Round-6 lesson: asm-held async register prefetch held across long spans is
// not spill-safe; here poll regs live only across the tag-guarded loop.
// ---------------------------------------------------------------------------

typedef __attribute__((ext_vector_type(8))) short short8;
typedef __attribute__((ext_vector_type(4))) float float4v;
typedef __attribute__((ext_vector_type(4))) unsigned int uint4v;
typedef __attribute__((ext_vector_type(4))) unsigned short ushort4v;

#define TT   2048
#define BB   64
#define HH   256
#define TBH  ((size_t)33554432)   // T*B*H
#define BH   ((size_t)16384)      // B*H

// workspace layout (bytes)
#define WS_WT    0u          // 1 MB    bf16 WT[1024][512]
#define WS_BVEC  1048576u    // 4 KB    fp32 bias[1024]
#define WS_HBUF  1052672u    // 128 KB  u32 hbuf[4][2][16][256] tagged cols
#define WS_CST   1183744u    // 64 KB   fp32 cstate[64][256]
#define WS_G     1249280u    // Tc*64*1024*2  bf16 G2 [R/4][1024][4]

__device__ inline unsigned short f2bf(float x) {
    unsigned u = __float_as_uint(x);
    unsigned r = (u + 0x7FFFu + ((u >> 16) & 1u)) >> 16;
    return (unsigned short)r;
}
__device__ inline float bf2f(unsigned short x) {
    return __uint_as_float((unsigned)x << 16);
}
__device__ inline float sigmoidf_(float x) { return 1.0f / (1.0f + __expf(-x)); }
__device__ inline float tanhf_(float x) {
    float e = __expf(-2.0f * fabsf(x));
    float t = (1.0f - e) / (1.0f + e);
    return copysignf(t, x);
}

// LDS-only workgroup barrier: orders ds ops (hsm/gbuf) without draining
// vmcnt (publish/out store-acks stay in flight across the barrier).
__device__ inline void bar_lds() {
    asm volatile("s_waitcnt lgkmcnt(0)\n\ts_barrier" ::: "memory");
}

__device__ inline bool tagok8(const uint4v& a, const uint4v& b, unsigned want) {
    return ((a[0] >> 16) == want) & ((a[1] >> 16) == want) &
           ((a[2] >> 16) == want) & ((a[3] >> 16) == want) &
           ((b[0] >> 16) == want) & ((b[1] >> 16) == want) &
           ((b[2] >> 16) == want) & ((b[3] >> 16) == want);
}

// ---------------------------------------------------------------------------
// Prep: WT[c][k] = W_gate(c/256)[k][c%256]  (bf16, k in [0,512)), bvec[c]=bias
// ---------------------------------------------------------------------------
__global__ void k_prep_w(const float* __restrict__ Wf, const float* __restrict__ Wi,
                         const float* __restrict__ Wg, const float* __restrict__ Wo,
                         const float* __restrict__ bf_, const float* __restrict__ bi_,
                         const float* __restrict__ bg_, const float* __restrict__ bo_,
                         unsigned short* __restrict__ WT, float* __restrict__ bvec)
{
    int c = blockIdx.x;            // 0..1023
    int gate = c >> 8, j = c & 255;
    const float* W  = (gate == 0) ? Wf : (gate == 1) ? Wi : (gate == 2) ? Wg : Wo;
    const float* bb = (gate == 0) ? bf_ : (gate == 1) ? bi_ : (gate == 2) ? bg_ : bo_;
    for (int k = threadIdx.x; k < 512; k += 256)
        WT[(size_t)c * 512 + k] = f2bf(W[(size_t)k * 256 + j]);
    if (threadIdx.x == 0) bvec[c] = bb[j];
}

__global__ void k_zero(unsigned int* __restrict__ hbuf, float* __restrict__ cst)
{
    int tid = blockIdx.x * blockDim.x + threadIdx.x;
    int nt = gridDim.x * blockDim.x;
    for (int i = tid; i < 32768; i += nt) hbuf[i] = 0u;  // 128 KB, tag 0 = h_{-1}=0
    for (int i = tid; i < 16384; i += nt) cst[i] = 0.f;  // 64 KB
}

// ---------------------------------------------------------------------------
// Phase 1: G2[r>>2][c][r&3] = bf16( sum_k X[r][k]*WT[c][k] + bvec[c] )
// 128x128 tile, 4 waves, BK=64, XOR-swizzled LDS, fp32->bf16 on the fly.
// ---------------------------------------------------------------------------
__global__ __launch_bounds__(256) void gemm_xw(
    const float* __restrict__ X,           // chunk base [R][256] fp32
    const unsigned short* __restrict__ WT, // [1024][512] bf16
    const float* __restrict__ bvec,
    unsigned short* __restrict__ G2)       // [R/4][1024][4] bf16 packed
{
    int col0 = blockIdx.x * 128;
    int row0 = blockIdx.y * 128;
    int tid = threadIdx.x, l = tid & 63, w = tid >> 6;
    int wr = w >> 1, wc = w & 1;

    __shared__ __align__(16) unsigned char asm_[16384];
    __shared__ __align__(16) unsigned char bsm_[16384];

    float4v acc[4][4];
#pragma unroll
    for (int i = 0; i < 4; ++i)
#pragma unroll
        for (int j = 0; j < 4; ++j) { acc[i][j][0] = 0.f; acc[i][j][1] = 0.f; acc[i][j][2] = 0.f; acc[i][j][3] = 0.f; }

    for (int kt = 0; kt < 4; ++kt) {
        // stage A (fp32 -> bf16): 128 rows x 64 k
        {
            int r = tid >> 1, seg = tid & 1;
            const float* src = X + (size_t)(row0 + r) * 256 + kt * 64 + seg * 32;
            short8 tmp[4];
#pragma unroll
            for (int v = 0; v < 4; ++v)
#pragma unroll
                for (int e = 0; e < 8; ++e) tmp[v][e] = (short)f2bf(src[v * 8 + e]);
            unsigned char* dst = asm_ + r * 128;
            int base = seg * 64, swz = (r & 7) << 4;
#pragma unroll
            for (int v = 0; v < 4; ++v)
                *(short8*)(dst + ((base + 16 * v) ^ swz)) = tmp[v];
        }
        // stage B (bf16 copy): 128 cols x 64 k
        {
            int c_ = tid >> 1, seg = tid & 1;
            const unsigned char* src = (const unsigned char*)WT + (size_t)(col0 + c_) * 1024 + kt * 128 + seg * 64;
            unsigned char* dst = bsm_ + c_ * 128;
            int base = seg * 64, swz = (c_ & 7) << 4;
#pragma unroll
            for (int v = 0; v < 4; ++v)
                *(short8*)(dst + ((base + 16 * v) ^ swz)) = *(const short8*)(src + 16 * v);
        }
        __syncthreads();
#pragma unroll
        for (int km = 0; km < 2; ++km) {
            short8 af[4], bfr[4];
            int kb = 16 * (l >> 4) + 64 * km, swz = (l & 7) << 4;
#pragma unroll
            for (int i = 0; i < 4; ++i)
                af[i] = *(const short8*)(asm_ + (wr * 64 + i * 16 + (l & 15)) * 128 + (kb ^ swz));
#pragma unroll
            for (int j = 0; j < 4; ++j)
                bfr[j] = *(const short8*)(bsm_ + (wc * 64 + j * 16 + (l & 15)) * 128 + (kb ^ swz));
#pragma unroll
            for (int i = 0; i < 4; ++i)
#pragma unroll
                for (int j = 0; j < 4; ++j)
                    acc[i][j] = __builtin_amdgcn_mfma_f32_16x16x32_bf16(af[i], bfr[j], acc[i][j], 0, 0, 0);
        }
        __syncthreads();
    }
    // epilogue: + bias, pack 4 row-values to bf16, one 8B store each
#pragma unroll
    for (int j = 0; j < 4; ++j) {
        int col = col0 + wc * 64 + j * 16 + (l & 15);
        float bias = bvec[col];
#pragma unroll
        for (int i = 0; i < 4; ++i) {
            int row = row0 + wr * 64 + i * 16 + (l >> 4) * 4;   // row % 4 == 0
            ushort4v v;
            v[0] = f2bf(acc[i][j][0] + bias);
            v[1] = f2bf(acc[i][j][1] + bias);
            v[2] = f2bf(acc[i][j][2] + bias);
            v[3] = f2bf(acc[i][j][3] + bias);
            *(ushort4v*)(G2 + ((size_t)(row >> 2) * 1024 + col) * 4) = v;
        }
    }
}

// ---------------------------------------------------------------------------
// Phase 2: persistent recurrent kernel for a chunk of Tc steps.
// Grid 64 blocks x 512 thr; g = wg&7 (>=4 -> exit), s = wg>>3.
// Wave w: gate = w&3, dh = w>>2 -> 16 cols; weights in 32 regs/lane (AGPRs).
// ---------------------------------------------------------------------------
__global__ __launch_bounds__(512, 1) void lstm_rec(
    const unsigned short* __restrict__ G2,  // [Tc*16][1024][4] bf16 packed
    const unsigned short* __restrict__ WT,  // [1024][512] bf16
    float* __restrict__ out,
    unsigned int* __restrict__ hbuf,        // [4][2][16][256] tagged cols
    float* __restrict__ cstate,             // [64][256] fp32
    int t0, int Tc)
{
    int wg = blockIdx.x;
    int g = wg & 7;
    if (g >= 4) return;
    int s = wg >> 3;                  // 0..7

    int tid = threadIdx.x, l = tid & 63, w = tid >> 6;
    int gate = w & 3, dh = w >> 2;
    int c_lane = gate * 256 + s * 32 + dh * 16 + (l & 15);

    __shared__ __align__(16) unsigned char hsm[8192];   // h tile [16][256] bf16, swizzled
    __shared__ float gbuf[4][16][32];                   // pre-activations

    // weights -> registers: k bytes [512,1024) of WT row c_lane
    short8 bw[8];
    {
        const unsigned char* wp_ = (const unsigned char*)WT + (size_t)c_lane * 1024 + 512 + 16 * (l >> 4);
#pragma unroll
        for (int kk = 0; kk < 8; ++kk) bw[kk] = *(const short8*)(wp_ + 64 * kk);
    }

    // per-thread combine/publish element: row b_ (0..15), col j_ (0..31)
    int b_ = tid >> 5, j_ = tid & 31;
    float creg = cstate[(size_t)(g * 16 + b_) * 256 + s * 32 + j_];

    // poll/staging mapping: row srow (0..15), 8-col block sblk (0..31)
    int srow = tid >> 5, sblk = tid & 31;
    unsigned char* hsm_dst = hsm + srow * 512 + ((sblk * 16) ^ ((srow & 7) << 4));

    for (int tl = 0; tl < Tc; ++tl) {
        int tg = t0 + tl;
        int par = tg & 1, rpar = par ^ 1;

        // G preload: ONE 8B packed load, issued before the poll; drained by
        // the poll's first vmcnt(2) (it is older than both poll pairs).
        ushort4v gv;
        {
            const unsigned short* Gp = G2 +
                (((size_t)((tl * 64 + g * 16) >> 2) + (l >> 4)) * 1024 + c_lane) * 4;
            gv = *(const ushort4v*)Gp;
        }
        // spin-read h_{tg-1}: PIPELINED 2-DEEP poll. Two pairs (A,B) kept in
        // flight; each check waits vmcnt(2) = drains the older pair + all
        // older ops (stores, G, leftovers). Sampling period ~RTT/2.
        // Every acceptance is per-u32 tag-guarded -> fail-safe against
        // un-landed registers / WAW leftovers / mid-check overwrites (any
        // same-tag snapshot is bit-identical; wrong tag just retries).
        {
            const unsigned int* wp = hbuf + ((size_t)((g * 2 + rpar) * 16) + srow) * 256 + sblk * 8;
            unsigned want = (unsigned)tg;
            short8 hv;
            uint4v a0, a1, b0, b1;
            asm volatile("global_load_dwordx4 %0, %2, off sc1\n\t"
                         "global_load_dwordx4 %1, %3, off sc1"
                         : "=&v"(a0), "=&v"(a1) : "v"(wp), "v"(wp + 4) : "memory");
            asm volatile("global_load_dwordx4 %0, %2, off sc1\n\t"
                         "global_load_dwordx4 %1, %3, off sc1"
                         : "=&v"(b0), "=&v"(b1) : "v"(wp), "v"(wp + 4) : "memory");
            for (;;) {
                asm volatile("s_waitcnt vmcnt(2)" ::: "memory");
                __builtin_amdgcn_sched_barrier(0);
                if (tagok8(a0, a1, want)) {
                    hv[0] = (short)(a0[0] & 0xffffu);
                    hv[1] = (short)(a0[1] & 0xffffu);
                    hv[2] = (short)(a0[2] & 0xffffu);
                    hv[3] = (short)(a0[3] & 0xffffu);
                    hv[4] = (short)(a1[0] & 0xffffu);
                    hv[5] = (short)(a1[1] & 0xffffu);
                    hv[6] = (short)(a1[2] & 0xffffu);
                    hv[7] = (short)(a1[3] & 0xffffu);
                    break;
                }
                asm volatile("global_load_dwordx4 %0, %2, off sc1\n\t"
                             "global_load_dwordx4 %1, %3, off sc1"
                             : "=&v"(a0), "=&v"(a1) : "v"(wp), "v"(wp + 4) : "memory");
                asm volatile("s_waitcnt vmcnt(2)" ::: "memory");
                __builtin_amdgcn_sched_barrier(0);
                if (tagok8(b0, b1, want)) {
                    hv[0] = (short)(b0[0] & 0xffffu);
                    hv[1] = (short)(b0[1] & 0xffffu);
                    hv[2] = (short)(b0[2] & 0xffffu);
                    hv[3] = (short)(b0[3] & 0xffffu);
                    hv[4] = (short)(b1[0] & 0xffffu);
                    hv[5] = (short)(b1[1] & 0xffffu);
                    hv[6] = (short)(b1[2] & 0xffffu);
                    hv[7] = (short)(b1[3] & 0xffffu);
                    break;
                }
                asm volatile("global_load_dwordx4 %0, %2, off sc1\n\t"
                             "global_load_dwordx4 %1, %3, off sc1"
                             : "=&v"(b0), "=&v"(b1) : "v"(wp), "v"(wp + 4) : "memory");
            }
            *(short8*)hsm_dst = hv;
            // leftover pair stays in flight; it is the oldest vmem op at the
            // next step's first vmcnt(2) and drains there for free.
        }
        // pin gv consumption AFTER the poll (blocks MachineLICM hoisting the
        // convert + its waitcnt above the poll). gv's load was drained by the
        // first vmcnt(2) (older than both pairs).
        asm volatile("" : "+v"(gv));
        float4v acc;
        acc[0] = bf2f(gv[0]);
        acc[1] = bf2f(gv[1]);
        acc[2] = bf2f(gv[2]);
        acc[3] = bf2f(gv[3]);
        bar_lds();   // bar1: hsm writes visible (LDS-only; vmem stays in flight)
        // pre += h @ Wh(cols): two independent 4-MFMA chains
        {
            int row = l & 15;
            const unsigned char* ap = hsm + row * 512;
            int kb0 = 16 * (l >> 4), swz = (row & 7) << 4;
            short8 af[8];
#pragma unroll
            for (int kk = 0; kk < 8; ++kk) af[kk] = *(const short8*)(ap + ((kb0 + 64 * kk) ^ swz));
            float4v acc1 = {0.f, 0.f, 0.f, 0.f};
#pragma unroll
            for (int kk = 0; kk < 4; ++kk) {
                acc  = __builtin_amdgcn_mfma_f32_16x16x32_bf16(af[kk],     bw[kk],     acc,  0, 0, 0);
                acc1 = __builtin_amdgcn_mfma_f32_16x16x32_bf16(af[kk + 4], bw[kk + 4], acc1, 0, 0, 0);
            }
            acc[0] += acc1[0]; acc[1] += acc1[1]; acc[2] += acc1[2]; acc[3] += acc1[3];
        }
        // publish pre-activations to LDS
        {
            int r0 = (l >> 4) * 4, cc = dh * 16 + (l & 15);
            gbuf[gate][r0 + 0][cc] = acc[0];
            gbuf[gate][r0 + 1][cc] = acc[1];
            gbuf[gate][r0 + 2][cc] = acc[2];
            gbuf[gate][r0 + 3][cc] = acc[3];
        }
        bar_lds();   // bar2: gbuf visible
        // combine: all 512 threads, one (b_, j_) element each
        {
            float f  = sigmoidf_(gbuf[0][b_][j_]);
            float i  = sigmoidf_(gbuf[1][b_][j_]);
            float gg = tanhf_(gbuf[2][b_][j_]);
            float o  = sigmoidf_(gbuf[3][b_][j_]);
            creg = f * creg + i * gg;
            float h = o * tanhf_(creg);
            // tagged publish ASAP (relaxed, agent): tag = tg+1
            unsigned word = ((unsigned)(tg + 1) << 16) | (unsigned)f2bf(h);
            __hip_atomic_store(hbuf + ((size_t)((g * 2 + par) * 16) + b_) * 256 + s * 32 + j_,
                               word, __ATOMIC_RELAXED, __HIP_MEMORY_SCOPE_AGENT);
            size_t orow = (size_t)tg * 64 + g * 16 + b_;
            out[orow * 256 + s * 32 + j_] = h;
            if (tg == TT - 1) {
                out[TBH + (size_t)(g * 16 + b_) * 256 + s * 32 + j_] = h;
                out[TBH + BH + (size_t)(g * 16 + b_) * 256 + s * 32 + j_] = creg;
            }
        }
        bar_lds();   // bar3: performance-load-bearing (round-12) — keeps
                     // waves phase-aligned at poll entry; protects hsm/gbuf
                     // reuse; store-acks drain inside the poll's vmcnt(2).
    }
    cstate[(size_t)(g * 16 + b_) * 256 + s * 32 + j_] = creg;
}

// ---------------------------------------------------------------------------
extern "C" void kernel_launch(void* const* d_in, const int* in_sizes, int n_in,
                              void* d_out, int out_size, void* d_ws, size_t ws_size,
                              hipStream_t stream)
{
    (void)in_sizes; (void)n_in; (void)out_size;
    const float* X   = (const float*)d_in[0];
    const float* Wf  = (const float*)d_in[1];
    const float* bf_ = (const float*)d_in[2];
    const float* Wi  = (const float*)d_in[3];
    const float* bi_ = (const float*)d_in[4];
    const float* Wg  = (const float*)d_in[5];
    const float* bg_ = (const float*)d_in[6];
    const float* Wo  = (const float*)d_in[7];
    const float* bo_ = (const float*)d_in[8];
    float* out = (float*)d_out;
    unsigned char* ws = (unsigned char*)d_ws;

    unsigned short* WT   = (unsigned short*)(ws + WS_WT);
    float*          bvec = (float*)(ws + WS_BVEC);
    unsigned int*   hbuf = (unsigned int*)(ws + WS_HBUF);
    float*          cst  = (float*)(ws + WS_CST);
    unsigned short* G2   = (unsigned short*)(ws + WS_G);

    // Tc = 512 (round-13: chunk gradient exhausted below this; 512 minimizes
    // launch overhead at identical per-step time). bf16 G chunk = 64 MB.
    size_t avail = ws_size > WS_G ? ws_size - WS_G : 0;
    int Tc = 8;
    const int cands[7] = {512, 256, 128, 64, 32, 16, 8};
    for (int i = 0; i < 7; ++i) {
        if ((size_t)cands[i] * 64 * 1024 * 2 <= avail) { Tc = cands[i]; break; }
    }

    k_prep_w<<<1024, 256, 0, stream>>>(Wf, Wi, Wg, Wo, bf_, bi_, bg_, bo_, WT, bvec);
    k_zero<<<64, 256, 0, stream>>>(hbuf, cst);

    for (int t0 = 0; t0 < TT; t0 += Tc) {
        int R = Tc * 64;
        gemm_xw<<<dim3(8, R / 128), 256, 0, stream>>>(X + (size_t)t0 * 64 * 256, WT, bvec, G2);
        lstm_rec<<<64, 512, 0, stream>>>(G2, WT, out, hbuf, cst, t0, Tc);
    }
}

// Round 15
// 3217.207 us; speedup vs baseline: 1.0937x; 1.0937x over previous
//
#include <hip/hip_runtime.h>

// ---------------------------------------------------------------------------
// LSTM  T=2048, B=64, D=256, H=256  (fp32 in/out, bf16 MFMA compute)
//
//   G[t,b,c] = x[t,b,:] @ Wx[:,c] + bias[c]          (parallel GEMM)
//   per step: pre[c] = G[t,b,c] + h[t-1] @ Wh[:,c]   (persistent recurrent krn)
//   gates f,i,g,o -> c = f*c + i*g ; h = o*tanh(c)
//
// Round-15 = round-11 RESTORED (3212us verified best: round-1 structure +
// Tc=512 + packed-bf16 G + launch_bounds(512,1) + serial tag-guarded poll +
// bar3) with ONE change: MFMA accumulation split 2x4 -> 4x2 chains + add
// tree (dependent-chain depth 4 -> 2 MFMAs; saves ~L_mfma*2 - 2 adds on the
// bar1->gbuf serial path). Pure fp32 reassociation; margin 4.2x.
// Round-14 lesson (REGRESSED +77us/chunk, absmax 0.0039->0.0156 near-thresh):
// 2-deep pipelined polling is a no-go — back-to-back pair issues land
// together (sampling period still ~RTT) while doubling UC traffic and
// slowing producer publishes; absmax drift disqualifies it outright.
// Round-13: chunk gradient exhausted (Tc=512 optimal). Round-12: bar3 is
// performance-load-bearing (+36% without). Round-11: VGPR_Count=40 fine —
// loop-invariant MFMA operands live in AGPRs; weights always resident.
//
// Recurrent kernel: 4 batch-groups (M=16) x 8 column-slice WGs (128 cols each).
// h exchange FENCE-FREE via self-describing u32 words:
//   word = (tag << 16) | bf16(h),  tag = t+1  (tags <= 2048 < 2^16)
// All exchange traffic uses the agent-scope UC path (bypasses per-XCD L2s ->
// correct for ANY workgroup placement; no L2-residency staleness, no fences).
// Poll = 2 CONCURRENT global_load_dwordx4 sc1 per thread (4 tagged u32 each),
// one vmcnt(0), retry both on any tag miss. "=&v" early-clobber +
// sched_barrier(0) after waits. Per-u32 tags make 16B tearing harmless.
// Termination: a word cannot advance past tag t until this reader's WG
// publishes t+1 (parity double buffer). Overwrite safety: publishing tag t+1
// requires having observed tag t from ALL slices => all finished reading t-1.
// In-loop barriers are s_waitcnt lgkmcnt(0); s_barrier (LDS-only ordering);
// publish/out store-acks drain inside the next poll's vmcnt(0).
// hbuf MUST be 128 KB (earlier sessions hung: 64 KB aliased cstate over tags).
// Mode-A (same-XCD L2 exchange) abandoned: sc0 polls can cache stale clean
// lines (livelock / silent cross-replay corruption) without L2 inv/wb ops.
// Round-8 lesson: HIP predefines ushort4 -> use ushort4v.
// Round-6 lesson: asm-held async register prefetch is not spill-safe.
// ---------------------------------------------------------------------------

typedef __attribute__((ext_vector_type(8))) short short8;
typedef __attribute__((ext_vector_type(4))) float float4v;
typedef __attribute__((ext_vector_type(4))) unsigned int uint4v;
typedef __attribute__((ext_vector_type(4))) unsigned short ushort4v;

#define TT   2048
#define BB   64
#define HH   256
#define TBH  ((size_t)33554432)   // T*B*H
#define BH   ((size_t)16384)      // B*H

// workspace layout (bytes)
#define WS_WT    0u          // 1 MB    bf16 WT[1024][512]
#define WS_BVEC  1048576u    // 4 KB    fp32 bias[1024]
#define WS_HBUF  1052672u    // 128 KB  u32 hbuf[4][2][16][256] tagged cols
#define WS_CST   1183744u    // 64 KB   fp32 cstate[64][256]
#define WS_G     1249280u    // Tc*64*1024*2  bf16 G2 [R/4][1024][4]

__device__ inline unsigned short f2bf(float x) {
    unsigned u = __float_as_uint(x);
    unsigned r = (u + 0x7FFFu + ((u >> 16) & 1u)) >> 16;
    return (unsigned short)r;
}
__device__ inline float bf2f(unsigned short x) {
    return __uint_as_float((unsigned)x << 16);
}
__device__ inline float sigmoidf_(float x) { return 1.0f / (1.0f + __expf(-x)); }
__device__ inline float tanhf_(float x) {
    float e = __expf(-2.0f * fabsf(x));
    float t = (1.0f - e) / (1.0f + e);
    return copysignf(t, x);
}

// LDS-only workgroup barrier: orders ds ops (hsm/gbuf) without draining
// vmcnt (publish/out store-acks stay in flight across the barrier).
__device__ inline void bar_lds() {
    asm volatile("s_waitcnt lgkmcnt(0)\n\ts_barrier" ::: "memory");
}

// ---------------------------------------------------------------------------
// Prep: WT[c][k] = W_gate(c/256)[k][c%256]  (bf16, k in [0,512)), bvec[c]=bias
// ---------------------------------------------------------------------------
__global__ void k_prep_w(const float* __restrict__ Wf, const float* __restrict__ Wi,
                         const float* __restrict__ Wg, const float* __restrict__ Wo,
                         const float* __restrict__ bf_, const float* __restrict__ bi_,
                         const float* __restrict__ bg_, const float* __restrict__ bo_,
                         unsigned short* __restrict__ WT, float* __restrict__ bvec)
{
    int c = blockIdx.x;            // 0..1023
    int gate = c >> 8, j = c & 255;
    const float* W  = (gate == 0) ? Wf : (gate == 1) ? Wi : (gate == 2) ? Wg : Wo;
    const float* bb = (gate == 0) ? bf_ : (gate == 1) ? bi_ : (gate == 2) ? bg_ : bo_;
    for (int k = threadIdx.x; k < 512; k += 256)
        WT[(size_t)c * 512 + k] = f2bf(W[(size_t)k * 256 + j]);
    if (threadIdx.x == 0) bvec[c] = bb[j];
}

__global__ void k_zero(unsigned int* __restrict__ hbuf, float* __restrict__ cst)
{
    int tid = blockIdx.x * blockDim.x + threadIdx.x;
    int nt = gridDim.x * blockDim.x;
    for (int i = tid; i < 32768; i += nt) hbuf[i] = 0u;  // 128 KB, tag 0 = h_{-1}=0
    for (int i = tid; i < 16384; i += nt) cst[i] = 0.f;  // 64 KB
}

// ---------------------------------------------------------------------------
// Phase 1: G2[r>>2][c][r&3] = bf16( sum_k X[r][k]*WT[c][k] + bvec[c] )
// 128x128 tile, 4 waves, BK=64, XOR-swizzled LDS, fp32->bf16 on the fly.
// ---------------------------------------------------------------------------
__global__ __launch_bounds__(256) void gemm_xw(
    const float* __restrict__ X,           // chunk base [R][256] fp32
    const unsigned short* __restrict__ WT, // [1024][512] bf16
    const float* __restrict__ bvec,
    unsigned short* __restrict__ G2)       // [R/4][1024][4] bf16 packed
{
    int col0 = blockIdx.x * 128;
    int row0 = blockIdx.y * 128;
    int tid = threadIdx.x, l = tid & 63, w = tid >> 6;
    int wr = w >> 1, wc = w & 1;

    __shared__ __align__(16) unsigned char asm_[16384];
    __shared__ __align__(16) unsigned char bsm_[16384];

    float4v acc[4][4];
#pragma unroll
    for (int i = 0; i < 4; ++i)
#pragma unroll
        for (int j = 0; j < 4; ++j) { acc[i][j][0] = 0.f; acc[i][j][1] = 0.f; acc[i][j][2] = 0.f; acc[i][j][3] = 0.f; }

    for (int kt = 0; kt < 4; ++kt) {
        // stage A (fp32 -> bf16): 128 rows x 64 k
        {
            int r = tid >> 1, seg = tid & 1;
            const float* src = X + (size_t)(row0 + r) * 256 + kt * 64 + seg * 32;
            short8 tmp[4];
#pragma unroll
            for (int v = 0; v < 4; ++v)
#pragma unroll
                for (int e = 0; e < 8; ++e) tmp[v][e] = (short)f2bf(src[v * 8 + e]);
            unsigned char* dst = asm_ + r * 128;
            int base = seg * 64, swz = (r & 7) << 4;
#pragma unroll
            for (int v = 0; v < 4; ++v)
                *(short8*)(dst + ((base + 16 * v) ^ swz)) = tmp[v];
        }
        // stage B (bf16 copy): 128 cols x 64 k
        {
            int c_ = tid >> 1, seg = tid & 1;
            const unsigned char* src = (const unsigned char*)WT + (size_t)(col0 + c_) * 1024 + kt * 128 + seg * 64;
            unsigned char* dst = bsm_ + c_ * 128;
            int base = seg * 64, swz = (c_ & 7) << 4;
#pragma unroll
            for (int v = 0; v < 4; ++v)
                *(short8*)(dst + ((base + 16 * v) ^ swz)) = *(const short8*)(src + 16 * v);
        }
        __syncthreads();
#pragma unroll
        for (int km = 0; km < 2; ++km) {
            short8 af[4], bfr[4];
            int kb = 16 * (l >> 4) + 64 * km, swz = (l & 7) << 4;
#pragma unroll
            for (int i = 0; i < 4; ++i)
                af[i] = *(const short8*)(asm_ + (wr * 64 + i * 16 + (l & 15)) * 128 + (kb ^ swz));
#pragma unroll
            for (int j = 0; j < 4; ++j)
                bfr[j] = *(const short8*)(bsm_ + (wc * 64 + j * 16 + (l & 15)) * 128 + (kb ^ swz));
#pragma unroll
            for (int i = 0; i < 4; ++i)
#pragma unroll
                for (int j = 0; j < 4; ++j)
                    acc[i][j] = __builtin_amdgcn_mfma_f32_16x16x32_bf16(af[i], bfr[j], acc[i][j], 0, 0, 0);
        }
        __syncthreads();
    }
    // epilogue: + bias, pack 4 row-values to bf16, one 8B store each
#pragma unroll
    for (int j = 0; j < 4; ++j) {
        int col = col0 + wc * 64 + j * 16 + (l & 15);
        float bias = bvec[col];
#pragma unroll
        for (int i = 0; i < 4; ++i) {
            int row = row0 + wr * 64 + i * 16 + (l >> 4) * 4;   // row % 4 == 0
            ushort4v v;
            v[0] = f2bf(acc[i][j][0] + bias);
            v[1] = f2bf(acc[i][j][1] + bias);
            v[2] = f2bf(acc[i][j][2] + bias);
            v[3] = f2bf(acc[i][j][3] + bias);
            *(ushort4v*)(G2 + ((size_t)(row >> 2) * 1024 + col) * 4) = v;
        }
    }
}

// ---------------------------------------------------------------------------
// Phase 2: persistent recurrent kernel for a chunk of Tc steps.
// Grid 64 blocks x 512 thr; g = wg&7 (>=4 -> exit), s = wg>>3.
// Wave w: gate = w&3, dh = w>>2 -> 16 cols; weights in 32 regs/lane (AGPRs).
// ---------------------------------------------------------------------------
__global__ __launch_bounds__(512, 1) void lstm_rec(
    const unsigned short* __restrict__ G2,  // [Tc*16][1024][4] bf16 packed
    const unsigned short* __restrict__ WT,  // [1024][512] bf16
    float* __restrict__ out,
    unsigned int* __restrict__ hbuf,        // [4][2][16][256] tagged cols
    float* __restrict__ cstate,             // [64][256] fp32
    int t0, int Tc)
{
    int wg = blockIdx.x;
    int g = wg & 7;
    if (g >= 4) return;
    int s = wg >> 3;                  // 0..7

    int tid = threadIdx.x, l = tid & 63, w = tid >> 6;
    int gate = w & 3, dh = w >> 2;
    int c_lane = gate * 256 + s * 32 + dh * 16 + (l & 15);

    __shared__ __align__(16) unsigned char hsm[8192];   // h tile [16][256] bf16, swizzled
    __shared__ float gbuf[4][16][32];                   // pre-activations

    // weights -> registers: k bytes [512,1024) of WT row c_lane
    short8 bw[8];
    {
        const unsigned char* wp_ = (const unsigned char*)WT + (size_t)c_lane * 1024 + 512 + 16 * (l >> 4);
#pragma unroll
        for (int kk = 0; kk < 8; ++kk) bw[kk] = *(const short8*)(wp_ + 64 * kk);
    }

    // per-thread combine/publish element: row b_ (0..15), col j_ (0..31)
    int b_ = tid >> 5, j_ = tid & 31;
    float creg = cstate[(size_t)(g * 16 + b_) * 256 + s * 32 + j_];

    // poll/staging mapping: row srow (0..15), 8-col block sblk (0..31)
    int srow = tid >> 5, sblk = tid & 31;
    unsigned char* hsm_dst = hsm + srow * 512 + ((sblk * 16) ^ ((srow & 7) << 4));

    for (int tl = 0; tl < Tc; ++tl) {
        int tg = t0 + tl;
        int par = tg & 1, rpar = par ^ 1;

        // G preload: ONE 8B packed load (4 row-values of c_lane), issued
        // before the poll; in flight during the poll RTT, drained by the
        // poll's vmcnt(0). Convert AFTER the poll (pinned below).
        ushort4v gv;
        {
            const unsigned short* Gp = G2 +
                (((size_t)((tl * 64 + g * 16) >> 2) + (l >> 4)) * 1024 + c_lane) * 4;
            gv = *(const ushort4v*)Gp;
        }
        // spin-read h_{tg-1}: 2 CONCURRENT dwordx4 sc1 (agent UC) loads,
        // one vmcnt(0) (also drains the G load + prior store-acks, all
        // overlapped with the load RTT); retry both on any tag miss.
        {
            const unsigned int* wp = hbuf + ((size_t)((g * 2 + rpar) * 16) + srow) * 256 + sblk * 8;
            unsigned want = (unsigned)tg;
            short8 hv;
            uint4v w0, w1;
            for (;;) {
                asm volatile("global_load_dwordx4 %0, %2, off sc1\n\t"
                             "global_load_dwordx4 %1, %3, off sc1\n\t"
                             "s_waitcnt vmcnt(0)"
                             : "=&v"(w0), "=&v"(w1)
                             : "v"(wp), "v"(wp + 4) : "memory");
                __builtin_amdgcn_sched_barrier(0);
                if (((w0[0] >> 16) == want) & ((w0[1] >> 16) == want) &
                    ((w0[2] >> 16) == want) & ((w0[3] >> 16) == want) &
                    ((w1[0] >> 16) == want) & ((w1[1] >> 16) == want) &
                    ((w1[2] >> 16) == want) & ((w1[3] >> 16) == want)) break;
            }
            hv[0] = (short)(w0[0] & 0xffffu);
            hv[1] = (short)(w0[1] & 0xffffu);
            hv[2] = (short)(w0[2] & 0xffffu);
            hv[3] = (short)(w0[3] & 0xffffu);
            hv[4] = (short)(w1[0] & 0xffffu);
            hv[5] = (short)(w1[1] & 0xffffu);
            hv[6] = (short)(w1[2] & 0xffffu);
            hv[7] = (short)(w1[3] & 0xffffu);
            *(short8*)hsm_dst = hv;
        }
        // pin gv consumption AFTER the poll (blocks MachineLICM hoisting the
        // convert + its waitcnt above the poll); poll's vmcnt(0) made gv valid.
        asm volatile("" : "+v"(gv));
        float4v acc;
        acc[0] = bf2f(gv[0]);
        acc[1] = bf2f(gv[1]);
        acc[2] = bf2f(gv[2]);
        acc[3] = bf2f(gv[3]);
        bar_lds();   // bar1: hsm writes visible (LDS-only; vmem stays in flight)
        // pre += h @ Wh(cols): FOUR independent 2-MFMA chains + add tree
        // (round-15: dep depth 4 -> 2 MFMAs on the bar1->gbuf serial path)
        {
            int row = l & 15;
            const unsigned char* ap = hsm + row * 512;
            int kb0 = 16 * (l >> 4), swz = (row & 7) << 4;
            short8 af[8];
#pragma unroll
            for (int kk = 0; kk < 8; ++kk) af[kk] = *(const short8*)(ap + ((kb0 + 64 * kk) ^ swz));
            float4v acc1 = {0.f, 0.f, 0.f, 0.f};
            float4v acc2 = {0.f, 0.f, 0.f, 0.f};
            float4v acc3 = {0.f, 0.f, 0.f, 0.f};
            acc  = __builtin_amdgcn_mfma_f32_16x16x32_bf16(af[0], bw[0], acc,  0, 0, 0);
            acc1 = __builtin_amdgcn_mfma_f32_16x16x32_bf16(af[2], bw[2], acc1, 0, 0, 0);
            acc2 = __builtin_amdgcn_mfma_f32_16x16x32_bf16(af[4], bw[4], acc2, 0, 0, 0);
            acc3 = __builtin_amdgcn_mfma_f32_16x16x32_bf16(af[6], bw[6], acc3, 0, 0, 0);
            acc  = __builtin_amdgcn_mfma_f32_16x16x32_bf16(af[1], bw[1], acc,  0, 0, 0);
            acc1 = __builtin_amdgcn_mfma_f32_16x16x32_bf16(af[3], bw[3], acc1, 0, 0, 0);
            acc2 = __builtin_amdgcn_mfma_f32_16x16x32_bf16(af[5], bw[5], acc2, 0, 0, 0);
            acc3 = __builtin_amdgcn_mfma_f32_16x16x32_bf16(af[7], bw[7], acc3, 0, 0, 0);
            acc1[0] += acc3[0]; acc1[1] += acc3[1]; acc1[2] += acc3[2]; acc1[3] += acc3[3];
            acc[0] += acc2[0]; acc[1] += acc2[1]; acc[2] += acc2[2]; acc[3] += acc2[3];
            acc[0] += acc1[0]; acc[1] += acc1[1]; acc[2] += acc1[2]; acc[3] += acc1[3];
        }
        // publish pre-activations to LDS
        {
            int r0 = (l >> 4) * 4, cc = dh * 16 + (l & 15);
            gbuf[gate][r0 + 0][cc] = acc[0];
            gbuf[gate][r0 + 1][cc] = acc[1];
            gbuf[gate][r0 + 2][cc] = acc[2];
            gbuf[gate][r0 + 3][cc] = acc[3];
        }
        bar_lds();   // bar2: gbuf visible
        // combine: all 512 threads, one (b_, j_) element each
        {
            float f  = sigmoidf_(gbuf[0][b_][j_]);
            float i  = sigmoidf_(gbuf[1][b_][j_]);
            float gg = tanhf_(gbuf[2][b_][j_]);
            float o  = sigmoidf_(gbuf[3][b_][j_]);
            creg = f * creg + i * gg;
            float h = o * tanhf_(creg);
            // tagged publish ASAP (relaxed, agent): tag = tg+1
            unsigned word = ((unsigned)(tg + 1) << 16) | (unsigned)f2bf(h);
            __hip_atomic_store(hbuf + ((size_t)((g * 2 + par) * 16) + b_) * 256 + s * 32 + j_,
                               word, __ATOMIC_RELAXED, __HIP_MEMORY_SCOPE_AGENT);
            size_t orow = (size_t)tg * 64 + g * 16 + b_;
            out[orow * 256 + s * 32 + j_] = h;
            if (tg == TT - 1) {
                out[TBH + (size_t)(g * 16 + b_) * 256 + s * 32 + j_] = h;
                out[TBH + BH + (size_t)(g * 16 + b_) * 256 + s * 32 + j_] = creg;
            }
        }
        bar_lds();   // bar3: performance-load-bearing (round-12) — keeps
                     // waves phase-aligned at poll entry; protects hsm/gbuf
                     // reuse; store-acks drain inside the poll's vmcnt(0).
    }
    cstate[(size_t)(g * 16 + b_) * 256 + s * 32 + j_] = creg;
}

// ---------------------------------------------------------------------------
extern "C" void kernel_launch(void* const* d_in, const int* in_sizes, int n_in,
                              void* d_out, int out_size, void* d_ws, size_t ws_size,
                              hipStream_t stream)
{
    (void)in_sizes; (void)n_in; (void)out_size;
    const float* X   = (const float*)d_in[0];
    const float* Wf  = (const float*)d_in[1];
    const float* bf_ = (const float*)d_in[2];
    const float* Wi  = (const float*)d_in[3];
    const float* bi_ = (const float*)d_in[4];
    const float* Wg  = (const float*)d_in[5];
    const float* bg_ = (const float*)d_in[6];
    const float* Wo  = (const float*)d_in[7];
    const float* bo_ = (const float*)d_in[8];
    float* out = (float*)d_out;
    unsigned char* ws = (unsigned char*)d_ws;

    unsigned short* WT   = (unsigned short*)(ws + WS_WT);
    float*          bvec = (float*)(ws + WS_BVEC);
    unsigned int*   hbuf = (unsigned int*)(ws + WS_HBUF);
    float*          cst  = (float*)(ws + WS_CST);
    unsigned short* G2   = (unsigned short*)(ws + WS_G);

    // Tc = 512 (round-13: chunk gradient exhausted below this; 512 minimizes
    // launch overhead at identical per-step time). bf16 G chunk = 64 MB.
    size_t avail = ws_size > WS_G ? ws_size - WS_G : 0;
    int Tc = 8;
    const int cands[7] = {512, 256, 128, 64, 32, 16, 8};
    for (int i = 0; i < 7; ++i) {
        if ((size_t)cands[i] * 64 * 1024 * 2 <= avail) { Tc = cands[i]; break; }
    }

    k_prep_w<<<1024, 256, 0, stream>>>(Wf, Wi, Wg, Wo, bf_, bi_, bg_, bo_, WT, bvec);
    k_zero<<<64, 256, 0, stream>>>(hbuf, cst);

    for (int t0 = 0; t0 < TT; t0 += Tc) {
        int R = Tc * 64;
        gemm_xw<<<dim3(8, R / 128), 256, 0, stream>>>(X + (size_t)t0 * 64 * 256, WT, bvec, G2);
        lstm_rec<<<64, 512, 0, stream>>>(G2, WT, out, hbuf, cst, t0, Tc);
    }
}